// Round 8
// baseline (327.180 us; speedup 1.0000x reference)
//
#include <hip/hip_runtime.h>
#include <math.h>

#define M 64
#define B 256
#define T 256

typedef float f32x4 __attribute__((ext_vector_type(4)));

__device__ __forceinline__ float wave_sum64(float v) {
    #pragma unroll
    for (int m = 32; m >= 1; m >>= 1) v += __shfl_xor(v, m);
    return v;
}

// One kernel, self-timed per batch. Block (b, sp) reduces its 512-row slice,
// publishes partials (release), spins until all 8 blocks of batch b published
// (acquire), then finalizes batch b redundantly and stream-writes its slice
// with NT stores (mem re-read is L3-hot since NT stores don't allocate).
__global__ __launch_bounds__(T) void k_all(
    const float* __restrict__ mem, const float* __restrict__ hidden,
    const float* __restrict__ role1, const float* __restrict__ role2,
    const float* __restrict__ filer, const float* __restrict__ W_gate,
    const float* __restrict__ b_gate, float* __restrict__ prev_part,
    float* __restrict__ ss_part, int* __restrict__ cnt,
    float* __restrict__ out)
{
    const int b   = blockIdx.x >> 3;
    const int sp  = blockIdx.x & 7;
    const int tid = threadIdx.x;

    __shared__ float  role_s[512];
    __shared__ float4 part[4][16];
    __shared__ float  ss_lds[4];
    __shared__ float  c2_s[M];
    __shared__ float  inv_s;

    for (int i = tid; i < 512; i += T) {
        const int rt = sp * 512 + i;
        role_s[i] = role1[b * M + (rt >> 6)] * role2[b * M + (rt & 63)];
    }
    __syncthreads();

    const float4* mem4 = (const float4*)(mem + (size_t)b * 262144);
    const int f4 = tid & 15, rsub = tid >> 4;

    // ---- phase 1: partial prev_info[f] and sum(mem^2) over the slice ----
    float4 ap = make_float4(0.f, 0.f, 0.f, 0.f);
    float  ss = 0.f;
    #pragma unroll 8
    for (int i = 0; i < 32; ++i) {
        const int lrt = rsub + i * 16;
        const float4 v = mem4[(sp * 512 + lrt) * 16 + f4];
        const float  r = role_s[lrt];
        ap.x = fmaf(r, v.x, ap.x);
        ap.y = fmaf(r, v.y, ap.y);
        ap.z = fmaf(r, v.z, ap.z);
        ap.w = fmaf(r, v.w, ap.w);
        ss = fmaf(v.x, v.x, ss);
        ss = fmaf(v.y, v.y, ss);
        ss = fmaf(v.z, v.z, ss);
        ss = fmaf(v.w, v.w, ss);
    }

    #pragma unroll
    for (int m = 16; m <= 32; m <<= 1) {
        ap.x += __shfl_xor(ap.x, m);
        ap.y += __shfl_xor(ap.y, m);
        ap.z += __shfl_xor(ap.z, m);
        ap.w += __shfl_xor(ap.w, m);
    }
    const float ssw = wave_sum64(ss);

    const int wave = tid >> 6, lane = tid & 63;
    if (lane < 16) part[wave][lane] = ap;
    if (lane == 0) ss_lds[wave] = ssw;
    __syncthreads();

    if (tid < 16) {
        float4 a0 = part[0][tid], a1 = part[1][tid], a2 = part[2][tid], a3 = part[3][tid];
        float4 s;
        s.x = (a0.x + a1.x) + (a2.x + a3.x);
        s.y = (a0.y + a1.y) + (a2.y + a3.y);
        s.z = (a0.z + a1.z) + (a2.z + a3.z);
        s.w = (a0.w + a1.w) + (a2.w + a3.w);
        ((float4*)prev_part)[(size_t)(b * 8 + sp) * 16 + tid] = s;
    }
    if (tid == 0)
        ss_part[b * 8 + sp] = (ss_lds[0] + ss_lds[1]) + (ss_lds[2] + ss_lds[3]);
    __syncthreads();

    // ---- publish (release) and wait for batch-mates (acquire) ----
    if (tid == 0) {
        __hip_atomic_fetch_add(&cnt[b], 1, __ATOMIC_RELEASE,
                               __HIP_MEMORY_SCOPE_AGENT);
        while (__hip_atomic_load(&cnt[b], __ATOMIC_ACQUIRE,
                                 __HIP_MEMORY_SCOPE_AGENT) < 8)
            __builtin_amdgcn_s_sleep(1);
    }
    __syncthreads();
    __threadfence();   // make partials from other XCDs visible to all waves

    // ---- finalize batch b (first wave, redundant per block) ----
    if (tid < M) {
        const int f = tid;
        float p = 0.f;
        #pragma unroll
        for (int s = 0; s < 8; ++s) p += prev_part[(size_t)(b * 8 + s) * M + f];
        float ssm = 0.f;
        #pragma unroll
        for (int s = 0; s < 8; ++s) ssm += ss_part[b * 8 + s];

        float g = 0.f;
        #pragma unroll
        for (int j = 0; j < 8; ++j)
            g = fmaf(hidden[(size_t)b * 512 + f + j * 64], W_gate[f + j * 64], g);
        g = wave_sum64(g);
        g = 1.f / (1.f + expf(-(g + b_gate[0] + 1.f)));

        const float fil = filer[b * M + f];
        const float cur = g * (fil - p);
        const float d1   = wave_sum64(p * cur);
        const float ssc  = wave_sum64(cur * cur);
        const float r1   = role1[b * M + f];
        const float r2   = role2[b * M + f];
        const float ssr1 = wave_sum64(r1 * r1);
        const float ssr2 = wave_sum64(r2 * r2);

        const float sc = 1.0f / (float)M;
        const float ns = ssm + 2.f * sc * d1 + sc * sc * ssr1 * ssr2 * ssc;
        const float inv = 1.0f / fmaxf(sqrtf(ns), 1.0f);
        c2_s[f] = cur * sc * inv;
        if (f == 0) inv_s = inv;
    }
    __syncthreads();

    // ---- phase 2: out = mem*inv + role*c2 (role_s reused; NT stores) ----
    const float  inv = inv_s;
    const float4 c   = ((const float4*)c2_s)[f4];
    f32x4* out4 = (f32x4*)(out + (size_t)b * 262144);
    #pragma unroll 8
    for (int i = 0; i < 32; ++i) {
        const int lrt = rsub + i * 16;
        const int idx = (sp * 512 + lrt) * 16 + f4;
        const float4 v = mem4[idx];
        const float  r = role_s[lrt];
        f32x4 o;
        o.x = fmaf(r, c.x, v.x * inv);
        o.y = fmaf(r, c.y, v.y * inv);
        o.z = fmaf(r, c.z, v.z * inv);
        o.w = fmaf(r, c.w, v.w * inv);
        __builtin_nontemporal_store(o, &out4[idx]);
    }
}

extern "C" void kernel_launch(void* const* d_in, const int* in_sizes, int n_in,
                              void* d_out, int out_size, void* d_ws, size_t ws_size,
                              hipStream_t stream) {
    const float* mem    = (const float*)d_in[0];
    const float* hidden = (const float*)d_in[1];
    const float* role1  = (const float*)d_in[2];
    const float* role2  = (const float*)d_in[3];
    const float* filer  = (const float*)d_in[4];
    const float* Wg     = (const float*)d_in[5];
    const float* bg     = (const float*)d_in[6];
    float* out = (float*)d_out;

    float* ws        = (float*)d_ws;
    float* prev_part = ws;            // 256*8*64 = 131072 floats
    float* ss_part   = ws + 131072;   // 256*8    =   2048 floats
    int*   cnt       = (int*)(ws + 133120);   // 256 ints

    hipMemsetAsync(cnt, 0, B * sizeof(int), stream);
    hipLaunchKernelGGL(k_all, dim3(B * 8), dim3(T), 0, stream,
                       mem, hidden, role1, role2, filer, Wg, bg,
                       prev_part, ss_part, cnt, out);
}

// Round 9
// 309.440 us; speedup vs baseline: 1.0573x; 1.0573x over previous
//
#include <hip/hip_runtime.h>
#include <math.h>

#define M 64
#define B 256
#define T 256
#define SLICES 16
#define ROWS 256   // rows per slice = 4096/SLICES

typedef float f32x4 __attribute__((ext_vector_type(4)));

__device__ __forceinline__ float wave_sum64(float v) {
    #pragma unroll
    for (int m = 32; m >= 1; m >>= 1) v += __shfl_xor(v, m);
    return v;
}

// Pipelined single kernel. Block (b, sl) reduces its 256-row slice, publishes
// partials via relaxed agent-scope atomic stores (coherence point; no cache
// maintenance), bumps cnt[b] (relaxed), spins relaxed until all 16 slices of
// batch b published, then finalizes redundantly and NT-writes its slice.
// Grid (4096) = 2x resident window -> read and write phases overlap at device
// level as blocks retire.
__global__ __launch_bounds__(T) void k_pipe(
    const float* __restrict__ mem, const float* __restrict__ hidden,
    const float* __restrict__ role1, const float* __restrict__ role2,
    const float* __restrict__ filer, const float* __restrict__ W_gate,
    const float* __restrict__ b_gate, float* __restrict__ prev_part,
    float* __restrict__ ss_part, int* __restrict__ cnt,
    float* __restrict__ out)
{
    const int b   = blockIdx.x >> 4;
    const int sl  = blockIdx.x & 15;
    const int tid = threadIdx.x;

    __shared__ float  role_s[ROWS];
    __shared__ float4 part[4][16];
    __shared__ float  ss_lds[4];
    __shared__ float  c2_s[M];
    __shared__ float  inv_s;

    for (int i = tid; i < ROWS; i += T) {
        const int rt = sl * ROWS + i;
        role_s[i] = role1[b * M + (rt >> 6)] * role2[b * M + (rt & 63)];
    }
    __syncthreads();

    const float4* mem4 = (const float4*)(mem + (size_t)b * 262144);
    const int f4 = tid & 15, rsub = tid >> 4;

    // ---- phase 1: partial prev_info[f] and sum(mem^2) over the slice ----
    float4 ap = make_float4(0.f, 0.f, 0.f, 0.f);
    float  ss = 0.f;
    #pragma unroll
    for (int i = 0; i < 16; ++i) {
        const int lrt = i * 16 + rsub;
        const float4 v = mem4[(sl * ROWS + lrt) * 16 + f4];
        const float  r = role_s[lrt];
        ap.x = fmaf(r, v.x, ap.x);
        ap.y = fmaf(r, v.y, ap.y);
        ap.z = fmaf(r, v.z, ap.z);
        ap.w = fmaf(r, v.w, ap.w);
        ss = fmaf(v.x, v.x, ss);
        ss = fmaf(v.y, v.y, ss);
        ss = fmaf(v.z, v.z, ss);
        ss = fmaf(v.w, v.w, ss);
    }

    #pragma unroll
    for (int m = 16; m <= 32; m <<= 1) {
        ap.x += __shfl_xor(ap.x, m);
        ap.y += __shfl_xor(ap.y, m);
        ap.z += __shfl_xor(ap.z, m);
        ap.w += __shfl_xor(ap.w, m);
    }
    const float ssw = wave_sum64(ss);

    const int wave = tid >> 6, lane = tid & 63;
    if (lane < 16) part[wave][lane] = ap;
    if (lane == 0) ss_lds[wave] = ssw;
    __syncthreads();

    // ---- publish partials (wave 0 only; relaxed agent atomics -> L3) ----
    if (tid < 16) {
        float4 a0 = part[0][tid], a1 = part[1][tid], a2 = part[2][tid], a3 = part[3][tid];
        const int base = (b * SLICES + sl) * M + 4 * tid;
        __hip_atomic_store(&prev_part[base + 0], (a0.x + a1.x) + (a2.x + a3.x),
                           __ATOMIC_RELAXED, __HIP_MEMORY_SCOPE_AGENT);
        __hip_atomic_store(&prev_part[base + 1], (a0.y + a1.y) + (a2.y + a3.y),
                           __ATOMIC_RELAXED, __HIP_MEMORY_SCOPE_AGENT);
        __hip_atomic_store(&prev_part[base + 2], (a0.z + a1.z) + (a2.z + a3.z),
                           __ATOMIC_RELAXED, __HIP_MEMORY_SCOPE_AGENT);
        __hip_atomic_store(&prev_part[base + 3], (a0.w + a1.w) + (a2.w + a3.w),
                           __ATOMIC_RELAXED, __HIP_MEMORY_SCOPE_AGENT);
    }
    if (tid == 0)
        __hip_atomic_store(&ss_part[b * SLICES + sl],
                           (ss_lds[0] + ss_lds[1]) + (ss_lds[2] + ss_lds[3]),
                           __ATOMIC_RELAXED, __HIP_MEMORY_SCOPE_AGENT);
    asm volatile("s_waitcnt vmcnt(0)" ::: "memory");
    if (tid == 0) {
        __hip_atomic_fetch_add(&cnt[b], 1, __ATOMIC_RELAXED,
                               __HIP_MEMORY_SCOPE_AGENT);
        while (__hip_atomic_load(&cnt[b], __ATOMIC_RELAXED,
                                 __HIP_MEMORY_SCOPE_AGENT) < SLICES)
            __builtin_amdgcn_s_sleep(4);
    }
    __syncthreads();

    // ---- finalize batch b (first wave, redundant per block) ----
    if (tid < M) {
        const int f = tid;
        float p = 0.f;
        #pragma unroll
        for (int s = 0; s < SLICES; ++s)
            p += prev_part[(size_t)(b * SLICES + s) * M + f];
        float ssm = 0.f;
        #pragma unroll
        for (int s = 0; s < SLICES; ++s) ssm += ss_part[b * SLICES + s];

        float g = 0.f;
        #pragma unroll
        for (int j = 0; j < 8; ++j)
            g = fmaf(hidden[(size_t)b * 512 + f + j * 64], W_gate[f + j * 64], g);
        g = wave_sum64(g);
        g = 1.f / (1.f + expf(-(g + b_gate[0] + 1.f)));

        const float fil = filer[b * M + f];
        const float cur = g * (fil - p);
        const float d1   = wave_sum64(p * cur);
        const float ssc  = wave_sum64(cur * cur);
        const float r1   = role1[b * M + f];
        const float r2   = role2[b * M + f];
        const float ssr1 = wave_sum64(r1 * r1);
        const float ssr2 = wave_sum64(r2 * r2);

        const float sc = 1.0f / (float)M;
        const float ns = ssm + 2.f * sc * d1 + sc * sc * ssr1 * ssr2 * ssc;
        const float inv = 1.0f / fmaxf(sqrtf(ns), 1.0f);
        c2_s[f] = cur * sc * inv;
        if (f == 0) inv_s = inv;
    }
    __syncthreads();

    // ---- phase 2: out = mem*inv + role*c2 (role_s reused; NT stores) ----
    const float  inv = inv_s;
    const float4 c   = ((const float4*)c2_s)[f4];
    f32x4* out4 = (f32x4*)(out + (size_t)b * 262144);
    #pragma unroll
    for (int i = 0; i < 16; ++i) {
        const int lrt = i * 16 + rsub;
        const int idx = (sl * ROWS + lrt) * 16 + f4;
        const float4 v = mem4[idx];
        const float  r = role_s[lrt];
        f32x4 o;
        o.x = fmaf(r, c.x, v.x * inv);
        o.y = fmaf(r, c.y, v.y * inv);
        o.z = fmaf(r, c.z, v.z * inv);
        o.w = fmaf(r, c.w, v.w * inv);
        __builtin_nontemporal_store(o, &out4[idx]);
    }
}

extern "C" void kernel_launch(void* const* d_in, const int* in_sizes, int n_in,
                              void* d_out, int out_size, void* d_ws, size_t ws_size,
                              hipStream_t stream) {
    const float* mem    = (const float*)d_in[0];
    const float* hidden = (const float*)d_in[1];
    const float* role1  = (const float*)d_in[2];
    const float* role2  = (const float*)d_in[3];
    const float* filer  = (const float*)d_in[4];
    const float* Wg     = (const float*)d_in[5];
    const float* bg     = (const float*)d_in[6];
    float* out = (float*)d_out;

    float* ws        = (float*)d_ws;
    float* prev_part = ws;            // 256*16*64 = 262144 floats
    float* ss_part   = ws + 262144;   // 256*16    =   4096 floats
    int*   cnt       = (int*)(ws + 266240);   // 256 ints

    hipMemsetAsync(cnt, 0, B * sizeof(int), stream);
    hipLaunchKernelGGL(k_pipe, dim3(B * SLICES), dim3(T), 0, stream,
                       mem, hidden, role1, role2, filer, Wg, bg,
                       prev_part, ss_part, cnt, out);
}

// Round 10
// 177.424 us; speedup vs baseline: 1.8441x; 1.7441x over previous
//
#include <hip/hip_runtime.h>
#include <math.h>

#define M 64
#define B 256
#define T 256
#define SLICES 16
#define ROWS 256          // rows per slice = 4096/SLICES
#define CHUNK 64          // batches per chunk
#define NCHUNK 4

typedef float f32x4 __attribute__((ext_vector_type(4)));

__device__ __forceinline__ float wave_sum64(float v) {
    #pragma unroll
    for (int m = 32; m >= 1; m >>= 1) v += __shfl_xor(v, m);
    return v;
}

// Reduce: block (b_local, sl) reduces 256-row slice sl of batch b0+b_local:
// partial prev_info[f], partial sum(mem^2).
__global__ __launch_bounds__(T) void k_reduce(
    const float* __restrict__ mem, const float* __restrict__ role1,
    const float* __restrict__ role2, float* __restrict__ prev_part,
    float* __restrict__ ss_part, int b0)
{
    const int b   = b0 + (blockIdx.x >> 4);
    const int sl  = blockIdx.x & 15;
    const int tid = threadIdx.x;

    __shared__ float  role_s[ROWS];
    __shared__ float4 part[4][16];
    __shared__ float  ss_lds[4];

    for (int i = tid; i < ROWS; i += T) {
        const int rt = sl * ROWS + i;
        role_s[i] = role1[b * M + (rt >> 6)] * role2[b * M + (rt & 63)];
    }
    __syncthreads();

    const float4* mem4 = (const float4*)(mem + (size_t)b * 262144);
    const int f4 = tid & 15, rsub = tid >> 4;

    float4 ap = make_float4(0.f, 0.f, 0.f, 0.f);
    float  ss = 0.f;
    #pragma unroll
    for (int i = 0; i < 16; ++i) {
        const int lrt = i * 16 + rsub;
        const float4 v = mem4[(sl * ROWS + lrt) * 16 + f4];
        const float  r = role_s[lrt];
        ap.x = fmaf(r, v.x, ap.x);
        ap.y = fmaf(r, v.y, ap.y);
        ap.z = fmaf(r, v.z, ap.z);
        ap.w = fmaf(r, v.w, ap.w);
        ss = fmaf(v.x, v.x, ss);
        ss = fmaf(v.y, v.y, ss);
        ss = fmaf(v.z, v.z, ss);
        ss = fmaf(v.w, v.w, ss);
    }

    #pragma unroll
    for (int m = 16; m <= 32; m <<= 1) {
        ap.x += __shfl_xor(ap.x, m);
        ap.y += __shfl_xor(ap.y, m);
        ap.z += __shfl_xor(ap.z, m);
        ap.w += __shfl_xor(ap.w, m);
    }
    const float ssw = wave_sum64(ss);

    const int wave = tid >> 6, lane = tid & 63;
    if (lane < 16) part[wave][lane] = ap;
    if (lane == 0) ss_lds[wave] = ssw;
    __syncthreads();

    if (tid < 16) {
        float4 a0 = part[0][tid], a1 = part[1][tid], a2 = part[2][tid], a3 = part[3][tid];
        float4 s;
        s.x = (a0.x + a1.x) + (a2.x + a3.x);
        s.y = (a0.y + a1.y) + (a2.y + a3.y);
        s.z = (a0.z + a1.z) + (a2.z + a3.z);
        s.w = (a0.w + a1.w) + (a2.w + a3.w);
        ((float4*)prev_part)[(size_t)(b * SLICES + sl) * 16 + tid] = s;
    }
    if (tid == 0)
        ss_part[b * SLICES + sl] = (ss_lds[0] + ss_lds[1]) + (ss_lds[2] + ss_lds[3]);
}

// Write: block (b_local, sl) finalizes batch b redundantly from partials,
// then writes its slice: out = mem*inv + role*c2. NT loads (single-use,
// L3-hot), REGULAR stores (thrash impossible: chunk working set << L3).
__global__ __launch_bounds__(T) void k_write(
    const float* __restrict__ mem, const float* __restrict__ hidden,
    const float* __restrict__ role1, const float* __restrict__ role2,
    const float* __restrict__ filer, const float* __restrict__ W_gate,
    const float* __restrict__ b_gate, const float* __restrict__ prev_part,
    const float* __restrict__ ss_part, float* __restrict__ out, int b0)
{
    const int b   = b0 + (blockIdx.x >> 4);
    const int sl  = blockIdx.x & 15;
    const int tid = threadIdx.x;

    __shared__ float role_s[ROWS];
    __shared__ float c2_s[M];
    __shared__ float inv_s;

    if (tid < M) {
        const int f = tid;
        float p = 0.f;
        #pragma unroll
        for (int s = 0; s < SLICES; ++s)
            p += prev_part[(size_t)(b * SLICES + s) * M + f];
        float ssm = 0.f;
        #pragma unroll
        for (int s = 0; s < SLICES; ++s) ssm += ss_part[b * SLICES + s];

        float g = 0.f;
        #pragma unroll
        for (int j = 0; j < 8; ++j)
            g = fmaf(hidden[(size_t)b * 512 + f + j * 64], W_gate[f + j * 64], g);
        g = wave_sum64(g);
        g = 1.f / (1.f + expf(-(g + b_gate[0] + 1.f)));

        const float fil = filer[b * M + f];
        const float cur = g * (fil - p);
        const float d1   = wave_sum64(p * cur);
        const float ssc  = wave_sum64(cur * cur);
        const float r1   = role1[b * M + f];
        const float r2   = role2[b * M + f];
        const float ssr1 = wave_sum64(r1 * r1);
        const float ssr2 = wave_sum64(r2 * r2);

        const float sc = 1.0f / (float)M;
        const float ns = ssm + 2.f * sc * d1 + sc * sc * ssr1 * ssr2 * ssc;
        const float inv = 1.0f / fmaxf(sqrtf(ns), 1.0f);
        c2_s[f] = cur * sc * inv;
        if (f == 0) inv_s = inv;
    }
    for (int i = tid; i < ROWS; i += T) {
        const int rt = sl * ROWS + i;
        role_s[i] = role1[b * M + (rt >> 6)] * role2[b * M + (rt & 63)];
    }
    __syncthreads();

    const float  inv = inv_s;
    const float4 cc  = ((const float4*)c2_s)[tid & 15];
    const f32x4* mem4 = (const f32x4*)(mem + (size_t)b * 262144);
    float4* out4 = (float4*)(out + (size_t)b * 262144);
    const int f4 = tid & 15, rsub = tid >> 4;

    #pragma unroll
    for (int i = 0; i < 16; ++i) {
        const int lrt = i * 16 + rsub;
        const int idx = (sl * ROWS + lrt) * 16 + f4;
        const f32x4 v = __builtin_nontemporal_load(&mem4[idx]);
        const float r = role_s[lrt];
        float4 o;
        o.x = fmaf(r, cc.x, v.x * inv);
        o.y = fmaf(r, cc.y, v.y * inv);
        o.z = fmaf(r, cc.z, v.z * inv);
        o.w = fmaf(r, cc.w, v.w * inv);
        out4[idx] = o;
    }
}

extern "C" void kernel_launch(void* const* d_in, const int* in_sizes, int n_in,
                              void* d_out, int out_size, void* d_ws, size_t ws_size,
                              hipStream_t stream) {
    const float* mem    = (const float*)d_in[0];
    const float* hidden = (const float*)d_in[1];
    const float* role1  = (const float*)d_in[2];
    const float* role2  = (const float*)d_in[3];
    const float* filer  = (const float*)d_in[4];
    const float* Wg     = (const float*)d_in[5];
    const float* bg     = (const float*)d_in[6];
    float* out = (float*)d_out;

    float* ws        = (float*)d_ws;
    float* prev_part = ws;            // 256*16*64 = 262144 floats
    float* ss_part   = ws + 262144;   // 256*16    =   4096 floats

    for (int c = 0; c < NCHUNK; ++c) {
        const int b0 = c * CHUNK;
        hipLaunchKernelGGL(k_reduce, dim3(CHUNK * SLICES), dim3(T), 0, stream,
                           mem, role1, role2, prev_part, ss_part, b0);
        hipLaunchKernelGGL(k_write, dim3(CHUNK * SLICES), dim3(T), 0, stream,
                           mem, hidden, role1, role2, filer, Wg, bg,
                           prev_part, ss_part, out, b0);
    }
}

// Round 11
// 130.861 us; speedup vs baseline: 2.5002x; 1.3558x over previous
//
#include <hip/hip_runtime.h>
#include <math.h>

#define M 64
#define B 256
#define T 256

typedef float f32x4 __attribute__((ext_vector_type(4)));

__device__ __forceinline__ float wave_sum64(float v) {
    #pragma unroll
    for (int m = 32; m >= 1; m >>= 1) v += __shfl_xor(v, m);
    return v;
}

// Fabric-traffic model (established R1-R10): total moved = 268 GB read +
// 268 GB re-read (L3-hit, but L3 hits cost the same fabric BW as HBM) +
// 263 GB write = 799 GB; at the 6.29 TB/s copy ceiling -> ~127 us floor.
// This kernel pair measures 131.9 us = 96% of that floor.
//
// K1: block (b, sp) reduces 512-row slice sp of batch b:
// partial prev_info[f] = sum_rt role[rt]*mem[b][rt][f]; partial sum(mem^2).
__global__ __launch_bounds__(T) void k_reduce(
    const float* __restrict__ mem, const float* __restrict__ role1,
    const float* __restrict__ role2, float* __restrict__ prev_part,
    float* __restrict__ ss_part)
{
    const int b   = blockIdx.x >> 3;
    const int sp  = blockIdx.x & 7;
    const int tid = threadIdx.x;

    __shared__ float  role_s[512];
    __shared__ float4 part[4][16];
    __shared__ float  ss_lds[4];

    for (int i = tid; i < 512; i += T) {
        const int rt = sp * 512 + i;
        role_s[i] = role1[b * M + (rt >> 6)] * role2[b * M + (rt & 63)];
    }
    __syncthreads();

    const float4* mem4 = (const float4*)(mem + (size_t)b * 262144);
    const int f4 = tid & 15, rsub = tid >> 4;

    float4 ap = make_float4(0.f, 0.f, 0.f, 0.f);
    float  ss = 0.f;
    #pragma unroll 8
    for (int i = 0; i < 32; ++i) {
        const int lrt = rsub + i * 16;
        const float4 v = mem4[(sp * 512 + lrt) * 16 + f4];
        const float  r = role_s[lrt];
        ap.x = fmaf(r, v.x, ap.x);
        ap.y = fmaf(r, v.y, ap.y);
        ap.z = fmaf(r, v.z, ap.z);
        ap.w = fmaf(r, v.w, ap.w);
        ss = fmaf(v.x, v.x, ss);
        ss = fmaf(v.y, v.y, ss);
        ss = fmaf(v.z, v.z, ss);
        ss = fmaf(v.w, v.w, ss);
    }

    #pragma unroll
    for (int m = 16; m <= 32; m <<= 1) {
        ap.x += __shfl_xor(ap.x, m);
        ap.y += __shfl_xor(ap.y, m);
        ap.z += __shfl_xor(ap.z, m);
        ap.w += __shfl_xor(ap.w, m);
    }
    const float ssw = wave_sum64(ss);

    const int wave = tid >> 6, lane = tid & 63;
    if (lane < 16) part[wave][lane] = ap;
    if (lane == 0) ss_lds[wave] = ssw;
    __syncthreads();

    if (tid < 16) {
        float4 a0 = part[0][tid], a1 = part[1][tid], a2 = part[2][tid], a3 = part[3][tid];
        float4 s;
        s.x = (a0.x + a1.x) + (a2.x + a3.x);
        s.y = (a0.y + a1.y) + (a2.y + a3.y);
        s.z = (a0.z + a1.z) + (a2.z + a3.z);
        s.w = (a0.w + a1.w) + (a2.w + a3.w);
        ((float4*)prev_part)[(size_t)(b * 8 + sp) * 16 + tid] = s;
    }
    if (tid == 0)
        ss_part[b * 8 + sp] = (ss_lds[0] + ss_lds[1]) + (ss_lds[2] + ss_lds[3]);
}

// K2: block (b, sp) redundantly finalizes batch b from partials (analytic
// norm: ||new||^2 = ||mem||^2 + 2/M*(prev.cur) + (1/M^2)||r1||^2||r2||^2||cur||^2),
// then writes out = mem*inv + role*c2 for its slice. NT stores are REQUIRED:
// they keep the L3-resident mem from being evicted by the output stream
// (regular stores: 164-177 us, R7/R10).
__global__ __launch_bounds__(T) void k_write(
    const float* __restrict__ mem, const float* __restrict__ hidden,
    const float* __restrict__ role1, const float* __restrict__ role2,
    const float* __restrict__ filer, const float* __restrict__ W_gate,
    const float* __restrict__ b_gate, const float* __restrict__ prev_part,
    const float* __restrict__ ss_part, float* __restrict__ out)
{
    const int b   = blockIdx.x >> 3;
    const int sp  = blockIdx.x & 7;
    const int tid = threadIdx.x;

    __shared__ float role_s[512];
    __shared__ float c2_s[M];
    __shared__ float inv_s;

    if (tid < M) {
        const int f = tid;
        float p = 0.f;
        #pragma unroll
        for (int s = 0; s < 8; ++s) p += prev_part[(size_t)(b * 8 + s) * M + f];
        float ssm = 0.f;
        #pragma unroll
        for (int s = 0; s < 8; ++s) ssm += ss_part[b * 8 + s];

        float g = 0.f;
        #pragma unroll
        for (int j = 0; j < 8; ++j)
            g = fmaf(hidden[(size_t)b * 512 + f + j * 64], W_gate[f + j * 64], g);
        g = wave_sum64(g);
        g = 1.f / (1.f + expf(-(g + b_gate[0] + 1.f)));

        const float fil = filer[b * M + f];
        const float cur = g * (fil - p);
        const float d1   = wave_sum64(p * cur);
        const float ssc  = wave_sum64(cur * cur);
        const float r1   = role1[b * M + f];
        const float r2   = role2[b * M + f];
        const float ssr1 = wave_sum64(r1 * r1);
        const float ssr2 = wave_sum64(r2 * r2);

        const float sc = 1.0f / (float)M;
        const float ns = ssm + 2.f * sc * d1 + sc * sc * ssr1 * ssr2 * ssc;
        const float inv = 1.0f / fmaxf(sqrtf(ns), 1.0f);
        c2_s[f] = cur * sc * inv;
        if (f == 0) inv_s = inv;
    }
    for (int i = tid; i < 512; i += T) {
        const int rt = sp * 512 + i;
        role_s[i] = role1[b * M + (rt >> 6)] * role2[b * M + (rt & 63)];
    }
    __syncthreads();

    const float  inv = inv_s;
    const float4 c   = ((const float4*)c2_s)[tid & 15];
    const float4* mem4 = (const float4*)(mem + (size_t)b * 262144);
    f32x4* out4 = (f32x4*)(out + (size_t)b * 262144);
    const int f4 = tid & 15, rsub = tid >> 4;

    #pragma unroll 8
    for (int i = 0; i < 32; ++i) {
        const int lrt = rsub + i * 16;
        const int idx = (sp * 512 + lrt) * 16 + f4;
        const float4 v = mem4[idx];
        const float  r = role_s[lrt];
        f32x4 o;
        o.x = fmaf(r, c.x, v.x * inv);
        o.y = fmaf(r, c.y, v.y * inv);
        o.z = fmaf(r, c.z, v.z * inv);
        o.w = fmaf(r, c.w, v.w * inv);
        __builtin_nontemporal_store(o, &out4[idx]);
    }
}

extern "C" void kernel_launch(void* const* d_in, const int* in_sizes, int n_in,
                              void* d_out, int out_size, void* d_ws, size_t ws_size,
                              hipStream_t stream) {
    const float* mem    = (const float*)d_in[0];
    const float* hidden = (const float*)d_in[1];
    const float* role1  = (const float*)d_in[2];
    const float* role2  = (const float*)d_in[3];
    const float* filer  = (const float*)d_in[4];
    const float* Wg     = (const float*)d_in[5];
    const float* bg     = (const float*)d_in[6];
    float* out = (float*)d_out;

    float* ws        = (float*)d_ws;
    float* prev_part = ws;            // 256*8*64 = 131072 floats
    float* ss_part   = ws + 131072;   // 256*8    =   2048 floats

    hipLaunchKernelGGL(k_reduce, dim3(B * 8), dim3(T), 0, stream,
                       mem, role1, role2, prev_part, ss_part);
    hipLaunchKernelGGL(k_write, dim3(B * 8), dim3(T), 0, stream,
                       mem, hidden, role1, role2, filer, Wg, bg,
                       prev_part, ss_part, out);
}